// Round 6
// baseline (180.170 us; speedup 1.0000x reference)
//
#include <hip/hip_runtime.h>

typedef __attribute__((ext_vector_type(8))) short short8v;
typedef __attribute__((ext_vector_type(4))) float f32x4;

#define INVLN2 1.4426950408889634f

__device__ __forceinline__ ushort f2bf(float f) {
  union { float f; unsigned int u; } c; c.f = f;
  return (ushort)((c.u + 0x7FFFu + ((c.u >> 16) & 1u)) >> 16);
}

__device__ __forceinline__ unsigned cvtpk(float a, float b) {
  unsigned r;
  asm("v_cvt_pk_bf16_f32 %0, %1, %2" : "=v"(r) : "v"(a), "v"(b));
  return r;
}

__device__ __forceinline__ float exp2w(float x) {
#if __has_builtin(__builtin_amdgcn_exp2f)
  return __builtin_amdgcn_exp2f(x);
#else
  return __expf(x * 0.6931471805599453f);
#endif
}

__device__ __forceinline__ short8v bits8(unsigned a, unsigned b, unsigned c, unsigned d) {
  union { unsigned u[4]; short8v s; } cv;
  cv.u[0] = a; cv.u[1] = b; cv.u[2] = c; cv.u[3] = d;
  return cv.s;
}

// ---- setup: bf16 weights (q rows pre-scaled by qs*INVLN2), scaled qkv bias,
// gathered rel-pos bias (*INVLN2)
__global__ __launch_bounds__(256) void setup_k(
    const float* __restrict__ qkv_w, const float* __restrict__ proj_w,
    const float* __restrict__ bias_table, const int* __restrict__ rel_idx,
    const float* __restrict__ qkv_b,
    ushort* __restrict__ qkv_wb, ushort* __restrict__ proj_wb,
    float* __restrict__ bias_comb, float* __restrict__ qkv_bs) {
  const float qs = 0.17677669529663687f * INVLN2;  // 1/sqrt(32) * 1/ln2
  int idx = blockIdx.x * 256 + threadIdx.x;
  if (idx < 27648) {                       // 288*96 (rows 0..95 = q)
    qkv_wb[idx] = f2bf(qkv_w[idx] * (idx < 9216 ? qs : 1.0f));
  } else if (idx < 36864) {                // + 96*96
    int i = idx - 27648;
    proj_wb[i] = f2bf(proj_w[i]);
  } else if (idx < 49152) {                // + 3*64*64
    int i = idx - 36864;
    int h = i / 4096, rc = i % 4096;
    bias_comb[i] = bias_table[rel_idx[rc] * 3 + h] * INVLN2;
  } else if (idx < 49440) {                // + 288 scaled qkv bias
    int i = idx - 49152;
    qkv_bs[i] = qkv_b[i] * (i < 96 ? qs : 1.0f);
  }
}

// ---- main fused kernel: one block per window PAIR {bb, bb+4096}.
// All LDS is write-once -> __syncthreads -> read-only (race-free by
// construction; q/P/O move between fragment layouts via register shfl).
// LDS = klds 26624 + vts 24576 = 51200 B -> target 3 blocks/CU.
__global__ __launch_bounds__(256, 3) void winattn(
    const float* __restrict__ x, const float* __restrict__ mask,
    const ushort* __restrict__ qkv_wb, const ushort* __restrict__ proj_wb,
    const float* __restrict__ bias_comb, const float* __restrict__ qkv_bs,
    const float* __restrict__ proj_b, float* __restrict__ out) {
  __shared__ ushort klds[2][64][104];  // k row-major [token][chan] (write-once)
  __shared__ ushort vts[2][96][64];    // v^T [chan][token], XOR-swizzled (write-once)

  const int bb = blockIdx.x;           // 0..4095
  const int t = threadIdx.x;
  const int w = t >> 6;
  const int lane = t & 63;
  const int l15 = lane & 15;
  const int g = lane >> 4;
  const int qrow = w * 16 + l15;       // this lane's q-token (all phases)

  const bool ghi = (g >= 2);
  const int srcA = l15 + 16 * ((g & 1) * 2);
  const int srcB = srcA + 16;

  // phase A: x A-fragments for both windows (rows w*16+l15)
  short8v xa[2][3];
  #pragma unroll
  for (int u = 0; u < 2; ++u) {
    const float* xr = x + ((size_t)(bb + u * 4096) * 64 + qrow) * 96 + g * 8;
    #pragma unroll
    for (int ks3 = 0; ks3 < 3; ++ks3) {
      float4 a0 = *reinterpret_cast<const float4*>(xr + ks3 * 32);
      float4 a1 = *reinterpret_cast<const float4*>(xr + ks3 * 32 + 4);
      xa[u][ks3] = bits8(cvtpk(a0.x, a0.y), cvtpk(a0.z, a0.w),
                         cvtpk(a1.x, a1.y), cvtpk(a1.z, a1.w));
    }
  }

  // phase B1: q (swapped mfma -> token-local D), packed into registers
  unsigned qpk[2][6][2];
  #pragma unroll
  for (int nt = 0; nt < 6; ++nt) {
    short8v bf[3];
    #pragma unroll
    for (int ks3 = 0; ks3 < 3; ++ks3)
      bf[ks3] = *reinterpret_cast<const short8v*>(qkv_wb + (nt * 16 + l15) * 96 + ks3 * 32 + g * 8);
    float4 qb = *reinterpret_cast<const float4*>(qkv_bs + nt * 16 + g * 4);
    #pragma unroll
    for (int u = 0; u < 2; ++u) {
      f32x4 acc = {0.f, 0.f, 0.f, 0.f};
      #pragma unroll
      for (int ks3 = 0; ks3 < 3; ++ks3)
        acc = __builtin_amdgcn_mfma_f32_16x16x32_bf16(bf[ks3], xa[u][ks3], acc, 0, 0, 0);
      qpk[u][nt][0] = cvtpk(acc[0] + qb.x, acc[1] + qb.y);
      qpk[u][nt][1] = cvtpk(acc[2] + qb.z, acc[3] + qb.w);
    }
  }
  // q redistribution to QK^T B-fragments (register-only shfl, no LDS)
  short8v qf[2][3];
  #pragma unroll
  for (int u = 0; u < 2; ++u)
    #pragma unroll
    for (int h = 0; h < 3; ++h) {
      unsigned dm[4];
      #pragma unroll
      for (int m = 0; m < 4; ++m) {
        const int sl = (m < 2) ? srcA : srcB;
        unsigned lo = __shfl(qpk[u][2 * h + 0][m & 1], sl);
        unsigned hi = __shfl(qpk[u][2 * h + 1][m & 1], sl);
        dm[m] = ghi ? hi : lo;
      }
      qf[u][h] = bits8(dm[0], dm[1], dm[2], dm[3]);
    }

  // phase B2: k (swapped) -> klds rows w*16+l15 (write-once, own rows)
  #pragma unroll
  for (int nt = 6; nt < 12; ++nt) {
    short8v bf[3];
    #pragma unroll
    for (int ks3 = 0; ks3 < 3; ++ks3)
      bf[ks3] = *reinterpret_cast<const short8v*>(qkv_wb + (nt * 16 + l15) * 96 + ks3 * 32 + g * 8);
    float4 qb = *reinterpret_cast<const float4*>(qkv_bs + nt * 16 + g * 4);
    #pragma unroll
    for (int u = 0; u < 2; ++u) {
      f32x4 acc = {0.f, 0.f, 0.f, 0.f};
      #pragma unroll
      for (int ks3 = 0; ks3 < 3; ++ks3)
        acc = __builtin_amdgcn_mfma_f32_16x16x32_bf16(bf[ks3], xa[u][ks3], acc, 0, 0, 0);
      uint2 pk = make_uint2(cvtpk(acc[0] + qb.x, acc[1] + qb.y),
                            cvtpk(acc[2] + qb.z, acc[3] + qb.w));
      *reinterpret_cast<uint2*>(&klds[u][qrow][(nt - 6) * 16 + g * 4]) = pk;
    }
  }

  // phase B3: v (normal orientation -> [chan][token], XOR-swizzled b64 writes)
  #pragma unroll
  for (int nt = 12; nt < 18; ++nt) {
    const int cw = nt * 16 + l15;
    const int vc = cw - 192;                       // v-chan 0..95
    const int tk = (w * 16 + g * 4) ^ ((vc & 7) << 3);
    short8v bf[3];
    #pragma unroll
    for (int ks3 = 0; ks3 < 3; ++ks3)
      bf[ks3] = *reinterpret_cast<const short8v*>(qkv_wb + cw * 96 + ks3 * 32 + g * 8);
    const float vb = qkv_bs[cw];
    #pragma unroll
    for (int u = 0; u < 2; ++u) {
      f32x4 acc = {0.f, 0.f, 0.f, 0.f};
      #pragma unroll
      for (int ks3 = 0; ks3 < 3; ++ks3)
        acc = __builtin_amdgcn_mfma_f32_16x16x32_bf16(xa[u][ks3], bf[ks3], acc, 0, 0, 0);
      uint2 pk = make_uint2(cvtpk(acc[0] + vb, acc[1] + vb),
                            cvtpk(acc[2] + vb, acc[3] + vb));
      *reinterpret_cast<uint2*>(&vts[u][vc][tk]) = pk;
    }
  }

  // preload shift mask (shared by both windows & all heads), *INVLN2;
  // issued before the barrier so HBM latency overlaps the QKV tail.
  const float* mrow = mask + (size_t)bb * 4096 + qrow * 64;
  float mk[4][4];
  #pragma unroll
  for (int tj = 0; tj < 4; ++tj) {
    float4 m4 = *reinterpret_cast<const float4*>(mrow + tj * 16 + g * 4);
    mk[tj][0] = m4.x * INVLN2; mk[tj][1] = m4.y * INVLN2;
    mk[tj][2] = m4.z * INVLN2; mk[tj][3] = m4.w * INVLN2;
  }

  __syncthreads();   // publish klds + vts (the only barrier)

  const float* bcb0 = bias_comb + qrow * 64;
  short8v ofv[3][2];   // per-head normalized O A-fragments, stashed for proj

  #pragma unroll
  for (int h = 0; h < 3; ++h) {
    // QK^T swapped: lane holds S[q=qrow][k=tj*16+g*4+r] (in exp2 domain)
    f32x4 s[2][4];
    #pragma unroll
    for (int tj = 0; tj < 4; ++tj) {
      #pragma unroll
      for (int u = 0; u < 2; ++u) {
        short8v kf = *reinterpret_cast<const short8v*>(&klds[u][tj * 16 + l15][h * 32 + g * 8]);
        f32x4 z = {0.f, 0.f, 0.f, 0.f};
        s[u][tj] = __builtin_amdgcn_mfma_f32_16x16x32_bf16(kf, qf[u][h], z, 0, 0, 0);
      }
    }
    // + (rel-pos bias + mask) [both pre-scaled by 1/ln2]; exp2; row-sum
    #pragma unroll
    for (int tj = 0; tj < 4; ++tj) {
      float4 bc4 = *reinterpret_cast<const float4*>(bcb0 + h * 4096 + tj * 16 + g * 4);
      float bm[4] = {bc4.x + mk[tj][0], bc4.y + mk[tj][1],
                     bc4.z + mk[tj][2], bc4.w + mk[tj][3]};
      #pragma unroll
      for (int u = 0; u < 2; ++u)
        #pragma unroll
        for (int r = 0; r < 4; ++r) s[u][tj][r] += bm[r];
    }
    float inv[2];
    #pragma unroll
    for (int u = 0; u < 2; ++u) {
      #pragma unroll
      for (int tj = 0; tj < 4; ++tj)
        #pragma unroll
        for (int r = 0; r < 4; ++r) s[u][tj][r] = exp2w(s[u][tj][r]);
      float sm = ((s[u][0][0] + s[u][0][1]) + (s[u][0][2] + s[u][0][3]))
               + ((s[u][1][0] + s[u][1][1]) + (s[u][1][2] + s[u][1][3]))
               + ((s[u][2][0] + s[u][2][1]) + (s[u][2][2] + s[u][2][3]))
               + ((s[u][3][0] + s[u][3][1]) + (s[u][3][2] + s[u][3][3]));
      sm += __shfl_xor(sm, 16);
      sm += __shfl_xor(sm, 32);
      inv[u] = __builtin_amdgcn_rcpf(sm);
    }
    // pack P pairs, redistribute to PV B-fragments (register-only shfl)
    unsigned ppk[2][4][2];
    #pragma unroll
    for (int u = 0; u < 2; ++u)
      #pragma unroll
      for (int tj = 0; tj < 4; ++tj) {
        ppk[u][tj][0] = cvtpk(s[u][tj][0], s[u][tj][1]);
        ppk[u][tj][1] = cvtpk(s[u][tj][2], s[u][tj][3]);
      }
    short8v pfv[2][2];
    #pragma unroll
    for (int u = 0; u < 2; ++u)
      #pragma unroll
      for (int ks2 = 0; ks2 < 2; ++ks2) {
        unsigned dm[4];
        #pragma unroll
        for (int m = 0; m < 4; ++m) {
          const int sl = (m < 2) ? srcA : srcB;
          unsigned lo = __shfl(ppk[u][ks2 * 2 + 0][m & 1], sl);
          unsigned hi = __shfl(ppk[u][ks2 * 2 + 1][m & 1], sl);
          dm[m] = ghi ? hi : lo;
        }
        pfv[u][ks2] = bits8(dm[0], dm[1], dm[2], dm[3]);
      }
    // PV swapped: O[q=qrow][d], lane-local q again (swizzled vts reads)
    f32x4 oacc[2][2];
    #pragma unroll
    for (int u = 0; u < 2; ++u)
      #pragma unroll
      for (int nt = 0; nt < 2; ++nt) {
        const int vc = h * 32 + nt * 16 + l15;
        f32x4 o = {0.f, 0.f, 0.f, 0.f};
        #pragma unroll
        for (int ks2 = 0; ks2 < 2; ++ks2) {
          const int tk = (ks2 * 32 + g * 8) ^ ((vc & 7) << 3);
          short8v vf = *reinterpret_cast<const short8v*>(&vts[u][vc][tk]);
          o = __builtin_amdgcn_mfma_f32_16x16x32_bf16(vf, pfv[u][ks2], o, 0, 0, 0);
        }
        oacc[u][nt] = o;
      }
    // normalize+pack O, redistribute to proj A-fragments; stash for proj
    #pragma unroll
    for (int u = 0; u < 2; ++u) {
      unsigned opk[2][2];
      #pragma unroll
      for (int nt = 0; nt < 2; ++nt) {
        opk[nt][0] = cvtpk(oacc[u][nt][0] * inv[u], oacc[u][nt][1] * inv[u]);
        opk[nt][1] = cvtpk(oacc[u][nt][2] * inv[u], oacc[u][nt][3] * inv[u]);
      }
      unsigned dm[4];
      #pragma unroll
      for (int m = 0; m < 4; ++m) {
        const int sl = (m < 2) ? srcA : srcB;
        unsigned lo = __shfl(opk[0][m & 1], sl);
        unsigned hi = __shfl(opk[1][m & 1], sl);
        dm[m] = ghi ? hi : lo;
      }
      ofv[h][u] = bits8(dm[0], dm[1], dm[2], dm[3]);
    }
  }

  // output projection (all heads): pacc[u][nt2] = sum_h O_h @ Wp_h
  f32x4 pacc[2][6];
  #pragma unroll
  for (int u = 0; u < 2; ++u)
    #pragma unroll
    for (int nt2 = 0; nt2 < 6; ++nt2) pacc[u][nt2] = (f32x4){0.f, 0.f, 0.f, 0.f};
  #pragma unroll
  for (int h = 0; h < 3; ++h) {
    #pragma unroll
    for (int nt2 = 0; nt2 < 6; ++nt2) {
      short8v pfw = *reinterpret_cast<const short8v*>(proj_wb + (nt2 * 16 + l15) * 96 + h * 32 + g * 8);
      #pragma unroll
      for (int u = 0; u < 2; ++u)
        pacc[u][nt2] = __builtin_amdgcn_mfma_f32_16x16x32_bf16(ofv[h][u], pfw, pacc[u][nt2], 0, 0, 0);
    }
  }

  // epilogue: + proj bias, f32 stores for both windows
  float pb[6];
  #pragma unroll
  for (int nt2 = 0; nt2 < 6; ++nt2) pb[nt2] = proj_b[nt2 * 16 + l15];
  #pragma unroll
  for (int u = 0; u < 2; ++u) {
    float* ob = out + (size_t)(bb + u * 4096) * 6144 + (w * 16 + g * 4) * 96 + l15;
    #pragma unroll
    for (int nt2 = 0; nt2 < 6; ++nt2)
      #pragma unroll
      for (int r = 0; r < 4; ++r)
        ob[r * 96 + nt2 * 16] = pacc[u][nt2][r] + pb[nt2];
  }
}

extern "C" void kernel_launch(void* const* d_in, const int* in_sizes, int n_in,
                              void* d_out, int out_size, void* d_ws, size_t ws_size,
                              hipStream_t stream) {
  const float* x          = (const float*)d_in[0];
  const float* mask       = (const float*)d_in[1];
  const float* qkv_w      = (const float*)d_in[2];
  const float* qkv_b      = (const float*)d_in[3];
  const float* proj_w     = (const float*)d_in[4];
  const float* proj_b     = (const float*)d_in[5];
  const float* bias_table = (const float*)d_in[6];
  const int*   rel_idx    = (const int*)d_in[7];

  char* ws = (char*)d_ws;
  ushort* qkv_wb    = (ushort*)ws;                    // 288*96*2 = 55296 B
  ushort* proj_wb   = (ushort*)(ws + 55296);          // 96*96*2  = 18432 B
  float*  bias_comb = (float*)(ws + 55296 + 18432);   // 3*64*64*4 = 49152 B
  float*  qkv_bs    = (float*)(ws + 55296 + 18432 + 49152);  // 288*4 = 1152 B

  setup_k<<<194, 256, 0, stream>>>(qkv_w, proj_w, bias_table, rel_idx, qkv_b,
                                   qkv_wb, proj_wb, bias_comb, qkv_bs);
  winattn<<<4096, 256, 0, stream>>>(x, mask, qkv_wb, proj_wb,
                                    bias_comb, qkv_bs, proj_b, (float*)d_out);
}